// Round 14
// baseline (343.154 us; speedup 1.0000x reference)
//
#include <hip/hip_runtime.h>
#include <stdint.h>

typedef unsigned int u32;
typedef unsigned long long u64;
typedef unsigned short u16;
typedef unsigned char u8;

#define FDIM  128
#define NNODE 25000   // LDS sizing; N <= this
#define WG    1024
#define RB    64      // radix block threads (1 wave)
#define EPT   16      // radix elements per thread
#define RCHUNK (RB*EPT) // 1024 elements per radix block -> nb ~ 196 blocks
// rank fits 18 bits (E <= 262143); round tag in upper 14 bits, decreasing per round
#define KBITS 18
#define RMASK ((1u << KBITS) - 1u)
#define TAG(r) (((0x3FFFu - (u32)(r)) << KBITS))
#define PRROUNDS 4      // eager rounds 0..3 multi-block; k_match starts at round 4
#define CB 256
#define CEPT 4
#define CCHUNK (CB*CEPT)
#define HST (256*200)   // one shared hist buffer [256][nb], nb <= 200

// ---------- monotone float<->uint encoding (order-preserving, bijective) ----------
__device__ __forceinline__ u32 enc_f32(float f){
  u32 u = __float_as_uint(f);
  return (u & 0x80000000u) ? ~u : (u | 0x80000000u);
}
__device__ __forceinline__ float dec_f32(u32 u){
  u = (u & 0x80000000u) ? (u ^ 0x80000000u) : ~u;
  return __uint_as_float(u);
}
// NOTE (r11 lesson): filtered atomics (volatile pre-read + conditional atomic) FORCE
// uncached coherence-point reads -> 7MB FETCH and +21us in k_compact0. Plain
// fire-and-forget atomicMin/Max is latency-hidden. Do NOT "filter" atomics here.

// ---------- XLA CPU GenerateVF32Exp replica (DO NOT TOUCH - validated r1) ----------
__device__ __forceinline__ float xla_expf(float x){
  x = fminf(x,  88.3762626647950f);
  x = fmaxf(x, -88.3762626647949f);
  float fx = floorf(fmaf(x, 1.44269504088896341f, 0.5f));
  float tmp = __fmul_rn(fx, 0.693359375f);
  float zz  = __fmul_rn(fx, -2.12194440e-4f);
  x = __fsub_rn(x, tmp);
  x = __fsub_rn(x, zz);
  float z2 = __fmul_rn(x, x);
  float y = fmaf(1.9875691500E-4f, x, 1.3981999507E-3f);
  y = fmaf(y, x, 8.3334519073E-3f);
  y = fmaf(y, x, 4.1665795894E-2f);
  y = fmaf(y, x, 1.6666665459E-1f);
  y = fmaf(y, x, 5.0000001201E-1f);
  y = fmaf(y, z2, x);
  y = __fadd_rn(y, 1.0f);
  int n = (int)fx;
  float p2n = __uint_as_float((u32)(n + 127) << 23);
  return __fmul_rn(y, p2n);
}

// ---------- per-node dots (bit-identical sequential unfused order) + nmin/m_enc init ----------
__global__ __launch_bounds__(256) void k_dots(const float* __restrict__ x,
                      const float* __restrict__ wsrc, const float* __restrict__ wdst,
                      float* __restrict__ ds, float* __restrict__ dd,
                      u32* __restrict__ nmin, u32* __restrict__ m_enc, int N_)
{
  __shared__ float4 w4[64];
  int t = threadIdx.x;
  if (t < 32) w4[t] = ((const float4*)wsrc)[t];
  else if (t < 64) w4[t] = ((const float4*)wdst)[t - 32];
  __syncthreads();
  int v = blockIdx.x * blockDim.x + t;
  if (v >= N_) return;
  nmin[v] = 0xFFFFFFFFu;   // replaces 0xFF memset (consumed first by k_rscatP)
  m_enc[v] = 0u;           // replaces zero memset (consumed first by k_rawE)
  const float4* xr = (const float4*)(x + (size_t)v * FDIM);
  float accs = 0.f, accd = 0.f;
  #pragma unroll 4
  for (int k = 0; k < 32; ++k) {
    float4 xv = xr[k], w = w4[k], u = w4[k + 32];
    accs = __fadd_rn(accs, __fmul_rn(xv.x, w.x));
    accs = __fadd_rn(accs, __fmul_rn(xv.y, w.y));
    accs = __fadd_rn(accs, __fmul_rn(xv.z, w.z));
    accs = __fadd_rn(accs, __fmul_rn(xv.w, w.w));
    accd = __fadd_rn(accd, __fmul_rn(xv.x, u.x));
    accd = __fadd_rn(accd, __fmul_rn(xv.y, u.y));
    accd = __fadd_rn(accd, __fmul_rn(xv.z, u.z));
    accd = __fadd_rn(accd, __fmul_rn(xv.w, u.w));
  }
  ds[v] = accs; dd[v] = accd;
}

// ---------- per-edge raw + dst max + dst-sort keys + pass0 hist (LDS, col store + dtot) ----------
__global__ __launch_bounds__(RB) void k_rawE(const int* __restrict__ ei, const float* __restrict__ ds,
                       const float* __restrict__ dd, const float* __restrict__ bia,
                       float* __restrict__ raw, u32* __restrict__ m_enc,
                       u64* __restrict__ kvA, u32* __restrict__ hist, u32* __restrict__ dtot,
                       int nb, int E_)
{
  __shared__ u32 h[256];
  int t = threadIdx.x, b = blockIdx.x;
  for (int i = t; i < 256; i += RB) h[i] = 0;
  __syncthreads();
  int lo = b * RCHUNK + t * EPT;
  int hi = lo + EPT; if (hi > E_) hi = E_;
  float bv = bia[0];
  for (int e = lo; e < hi; ++e) {
    int s = ei[e], d = ei[E_ + e];
    float r = __fadd_rn(__fadd_rn(ds[s], dd[d]), bv);
    raw[e] = r;
    atomicMax(&m_enc[d], enc_f32(r));
    kvA[e] = ((u64)(u32)d << 32) | (u32)e;
    atomicAdd(&h[(u32)d & 255u], 1u);
  }
  __syncthreads();
  for (int i = t; i < 256; i += RB) { u32 c = h[i]; hist[(size_t)i * nb + b] = c; if (c) atomicAdd(&dtot[i], c); }
}

// ---------- radix: hist of one 8-bit digit (LDS aggregated, col store + dtot) ----------
__global__ __launch_bounds__(RB) void k_rhist(const u64* __restrict__ kv, u32* __restrict__ hist,
                                              u32* __restrict__ dtot, int n, int nb, int shift)
{
  __shared__ u32 h[256];
  int t = threadIdx.x, b = blockIdx.x;
  for (int i = t; i < 256; i += RB) h[i] = 0;
  __syncthreads();
  int lo = b * RCHUNK + t * EPT;
  int hi = lo + EPT; if (hi > n) hi = n;
  for (int i = lo; i < hi; ++i) atomicAdd(&h[((u32)(kv[i] >> 32) >> shift) & 255u], 1u);
  __syncthreads();
  for (int i = t; i < 256; i += RB) { u32 c = h[i]; hist[(size_t)i * nb + b] = c; if (c) atomicAdd(&dtot[i], c); }
}

// ---------- radix base: one block per digit; doff from dtot + own-row scan (r14:
// replaces the 2-dispatch multi-block scan; integer-identical positions) ----------
__global__ __launch_bounds__(256) void k_rbase(u32* __restrict__ hist, const u32* __restrict__ dtot, int nb)
{
  __shared__ u32 sh[256];
  __shared__ u32 s_doff;
  int t = threadIdx.x, dg = blockIdx.x;
  sh[t] = (t < dg) ? dtot[t] : 0u;
  __syncthreads();
  for (int off = 128; off > 0; off >>= 1) { if (t < off) sh[t] += sh[t + off]; __syncthreads(); }
  if (t == 0) s_doff = sh[0];
  __syncthreads();
  u32 v = (t < nb) ? hist[(size_t)dg * nb + t] : 0u;
  sh[t] = v; __syncthreads();
  for (int off = 1; off < 256; off <<= 1) {
    u32 a = (t >= off) ? sh[t - off] : 0u; __syncthreads();
    sh[t] += a; __syncthreads();
  }
  if (t < nb) hist[(size_t)dg * nb + t] = s_doff + sh[t] - v;   // exclusive prefix
}

// ---------- radix: stable scatter of u64 kv (key = high32) ----------
__global__ __launch_bounds__(RB) void k_rscat(const u64* __restrict__ kvin, u64* __restrict__ kvout,
                                              const u32* __restrict__ base, int n, int nb, int shift)
{
  __shared__ u16 h[RB][258];
  __shared__ u32 gbase[256];
  int t = threadIdx.x, b = blockIdx.x;
  for (int i = t; i < RB * 258 / 2; i += RB) ((u32*)h)[i] = 0u;
  __syncthreads();
  int lo = b * RCHUNK + t * EPT;
  int hi = lo + EPT; if (hi > n) hi = n;
  for (int i = lo; i < hi; ++i) { u32 d = ((u32)(kvin[i] >> 32) >> shift) & 255u; h[t][d]++; }
  __syncthreads();
  for (int dg = t; dg < 256; dg += RB) {   // each thread owns 4 digits
    u32 run = 0;
    for (int q = 0; q < RB; ++q) { u16 c = h[q][dg]; h[q][dg] = (u16)run; run += c; }
    gbase[dg] = base[(size_t)dg * nb + b];
  }
  __syncthreads();
  for (int i = lo; i < hi; ++i) {
    u64 kv = kvin[i];
    u32 d = ((u32)(kv >> 32) >> shift) & 255u;
    u32 p = gbase[d] + (u32)h[t][d];
    h[t][d]++;
    kvout[p] = kv;
  }
}

// ---------- final score-scatter fused with prep: per-rank metadata + round-0 mins ----------
__global__ __launch_bounds__(RB) void k_rscatP(const u64* __restrict__ kvin,
                                               const u32* __restrict__ base, int n, int nb, int shift,
                                               u32* __restrict__ pairByRank, float* __restrict__ scoreByRank,
                                               u8* __restrict__ chosen, u32* __restrict__ nmin)
{
  __shared__ u16 h[RB][258];
  __shared__ u32 gbase[256];
  int t = threadIdx.x, b = blockIdx.x;
  for (int i = t; i < RB * 258 / 2; i += RB) ((u32*)h)[i] = 0u;
  __syncthreads();
  int lo = b * RCHUNK + t * EPT;
  int hi = lo + EPT; if (hi > n) hi = n;
  for (int i = lo; i < hi; ++i) { u32 d = ((u32)(kvin[i] >> 32) >> shift) & 255u; h[t][d]++; }
  __syncthreads();
  for (int dg = t; dg < 256; dg += RB) {
    u32 run = 0;
    for (int q = 0; q < RB; ++q) { u16 c = h[q][dg]; h[q][dg] = (u16)run; run += c; }
    gbase[dg] = base[(size_t)dg * nb + b];
  }
  __syncthreads();
  for (int i = lo; i < hi; ++i) {
    u64 kv = kvin[i];
    u32 key = (u32)(kv >> 32);
    u32 d = (key >> shift) & 255u;
    u32 p = gbase[d] + (u32)h[t][d];
    h[t][d]++;
    u32 sd = (u32)kv;
    pairByRank[p] = sd;
    scoreByRank[p] = dec_f32(~key);   // enc bijective -> exact score bits
    chosen[p] = 0;
    u32 val = TAG(0) | p;
    atomicMin(&nmin[sd >> 16], val);
    atomicMin(&nmin[sd & 0xFFFFu], val);
  }
}

// ---------- softmax scores from dst-sorted kv segments (edge-id order in segment) ----------
__global__ void k_scores_seg(const u64* __restrict__ kvS, const float* __restrict__ raw,
                             const u32* __restrict__ m_enc, float* __restrict__ score, int E_)
{
  int i = blockIdx.x * blockDim.x + threadIdx.x;
  if (i >= E_) return;
  u32 d = (u32)(kvS[i] >> 32);
  if (i > 0 && (u32)(kvS[i - 1] >> 32) == d) return;   // not a segment head
  float m = dec_f32(m_enc[d]);
  float denom = 0.f;
  int j = i;
  while (j < E_) {
    u64 kv = kvS[j];
    if ((u32)(kv >> 32) != d) break;
    denom = __fadd_rn(denom, xla_expf(__fsub_rn(raw[(u32)kv], m)));
    ++j;
  }
  for (int q = i; q < j; ++q) {
    u32 e = (u32)kvS[q];
    float z = xla_expf(__fsub_rn(raw[e], m));
    score[e] = __fadd_rn(__fdiv_rn(z, denom), 0.5f);
  }
}

// ---------- score-sort keys + pass0 hist (LDS, col store + dtot) ----------
__global__ __launch_bounds__(RB) void k_key_score(const float* __restrict__ score, const int* __restrict__ ei,
                            u64* __restrict__ kvB, u32* __restrict__ hist, u32* __restrict__ dtot,
                            int nb, int E_)
{
  __shared__ u32 h[256];
  int t = threadIdx.x, b = blockIdx.x;
  for (int i = t; i < 256; i += RB) h[i] = 0;
  __syncthreads();
  int lo = b * RCHUNK + t * EPT;
  int hi = lo + EPT; if (hi > E_) hi = E_;
  for (int e = lo; e < hi; ++e) {
    u32 key = ~enc_f32(score[e]);   // ascending => descending score; stable => id asc
    u32 sd = ((u32)ei[e] << 16) | (u32)ei[E_ + e];
    kvB[e] = ((u64)key << 32) | sd;
    atomicAdd(&h[key & 255u], 1u);
  }
  __syncthreads();
  for (int i = t; i < 256; i += RB) { u32 c = h[i]; hist[(size_t)i * nb + b] = c; if (c) atomicAdd(&dtot[i], c); }
}

// ---------- eager round 0 choose, PER-NODE (r12) ----------
__global__ void k_choose0N(const u32* __restrict__ pairByRank, const u32* __restrict__ nmin,
                           u8* __restrict__ chosen, u8* __restrict__ matched_g, int N_)
{
  int v = blockIdx.x * blockDim.x + threadIdx.x;
  if (v >= N_) return;
  u32 mv = nmin[v];
  if (mv == 0xFFFFFFFFu) return;         // no incident edge
  u32 k = mv & RMASK;
  u32 sd = pairByRank[k];
  u32 s = sd >> 16, d = sd & 0xFFFFu;
  u32 other = ((u32)v == s) ? d : s;
  if (nmin[other] == mv) {
    matched_g[v] = 1;
    if ((u32)v == s) chosen[k] = 1;
  }
}

__global__ void k_compact0(const u32* __restrict__ pairByRank, const u8* __restrict__ matched_g,
                           u64* __restrict__ liveOut, u32* __restrict__ nmin,
                           u32* __restrict__ nlive, int E_)
{
  int k = blockIdx.x * blockDim.x + threadIdx.x;
  int lane = threadIdx.x & 63;
  bool liveE = false; u32 s = 0, d = 0;
  if (k < E_) {
    u32 sd = pairByRank[k];
    s = sd >> 16; d = sd & 0xFFFFu;
    liveE = (!matched_g[s] && !matched_g[d]);
  }
  u64 m = __ballot(liveE);
  if (m != 0ull) {
    int leader = __ffsll((long long)m) - 1;
    u32 base = 0;
    if (lane == leader) base = atomicAdd(nlive, (u32)__popcll(m));
    base = (u32)__shfl((int)base, leader);
    if (liveE) {
      u32 pfx = (u32)__popcll(m & ((1ull << lane) - 1ull));
      liveOut[base + pfx] = ((u64)(u32)k << 32) | ((u64)s << 16) | (u64)d;
      u32 nval = TAG(1) | (u32)k;
      atomicMin(&nmin[s], nval);
      atomicMin(&nmin[d], nval);
    }
  }
}

// ---------- eager pre-round r >= 1 ----------
__global__ void k_chooseR(const u64* __restrict__ liveIn, const u32* __restrict__ nliveIn,
                          const u32* __restrict__ nmin,
                          u8* __restrict__ chosen, u8* __restrict__ matched_g, u32 rtag)
{
  u32 i = blockIdx.x * blockDim.x + threadIdx.x;
  if (i >= *nliveIn) return;
  u64 v = liveIn[i];
  u32 k = (u32)(v >> 32), s = ((u32)v) >> 16, d = (u32)v & 0xFFFFu;
  u32 myval = rtag | k;
  if (nmin[s] == myval && nmin[d] == myval) { chosen[k] = 1; matched_g[s] = 1; matched_g[d] = 1; }
}

__global__ void k_compactR(const u64* __restrict__ liveIn, const u32* __restrict__ nliveIn,
                           const u8* __restrict__ matched_g,
                           u64* __restrict__ liveOut, u32* __restrict__ nmin,
                           u32* __restrict__ nliveOut, u32 ntag)
{
  u32 i = blockIdx.x * blockDim.x + threadIdx.x;
  int lane = threadIdx.x & 63;
  bool liveE = false; u64 v = 0; u32 s = 0, d = 0;
  if (i < *nliveIn) {
    v = liveIn[i];
    s = ((u32)v) >> 16; d = (u32)v & 0xFFFFu;
    liveE = (!matched_g[s] && !matched_g[d]);
  }
  u64 m = __ballot(liveE);
  if (m != 0ull) {
    int leader = __ffsll((long long)m) - 1;
    u32 base = 0;
    if (lane == leader) base = atomicAdd(nliveOut, (u32)__popcll(m));
    base = (u32)__shfl((int)base, leader);
    if (liveE) {
      u32 pfx = (u32)__popcll(m & ((1ull << lane) - 1ull));
      liveOut[base + pfx] = v;
      u32 nval = ntag | (u32)(v >> 32);
      atomicMin(&nmin[s], nval);
      atomicMin(&nmin[d], nval);
    }
  }
}

// ---------- single-block residual fixpoint (rounds >= PRROUNDS) ----------
__global__ __launch_bounds__(WG) void k_match(
    u64* liveA, u64* liveB, const u32* __restrict__ nmin_g, u8* __restrict__ matched_g,
    const u32* __restrict__ nliveIn, u8* __restrict__ chosen, int N_)
{
  __shared__ u32 node_min[NNODE];
  __shared__ u32 s_nlive, s_next;
  const int t = threadIdx.x;
  const int lane = t & 63;

  for (int i = t; i < N_; i += WG) node_min[i] = matched_g[i] ? 0u : nmin_g[i];
  if (t == 0) { s_nlive = *nliveIn; s_next = 0u; }
  __syncthreads();

  u64* LA = liveA; u64* LB = liveB;
  u32 r = PRROUNDS;
  while (true) {
    u32 nl = s_nlive;
    if (nl == 0u || r > 16000u) break;
    const u32 tag  = TAG(r);
    const u32 ntag = TAG(r + 1);

    for (u32 i = (u32)t; i < nl; i += WG) {
      u64 v = LA[i];
      u32 k = (u32)(v >> 32);
      u32 s = ((u32)v) >> 16, d = (u32)v & 0xFFFFu;
      u32 myval = tag | k;
      if (node_min[s] == myval && node_min[d] == myval) {
        chosen[k] = 1; node_min[s] = 0u; node_min[d] = 0u;
      }
    }
    __syncthreads();

    for (u32 i0 = (u32)(t & ~63); i0 < nl; i0 += WG) {
      u32 i = i0 + (u32)lane;
      bool liveE = false; u64 v = 0;
      u32 s = 0, d = 0;
      if (i < nl) {
        v = LA[i];
        s = ((u32)v) >> 16; d = (u32)v & 0xFFFFu;
        liveE = (node_min[s] != 0u && node_min[d] != 0u);
      }
      u64 m = __ballot(liveE);
      if (m != 0ull) {
        int leader = __ffsll((long long)m) - 1;
        u32 baseIdx = 0;
        if (lane == leader) baseIdx = atomicAdd(&s_next, (u32)__popcll(m));
        baseIdx = (u32)__shfl((int)baseIdx, leader);
        if (liveE) {
          u32 pfx = (u32)__popcll(m & ((1ull << lane) - 1ull));
          LB[baseIdx + pfx] = v;
          u32 nval = ntag | (u32)(v >> 32);
          atomicMin(&node_min[s], nval);
          atomicMin(&node_min[d], nval);
        }
      }
    }
    __syncthreads();
    if (t == 0) { s_nlive = s_next; s_next = 0u; }
    { u64* tmp = LA; LA = LB; LB = tmp; }
    ++r;
    __syncthreads();
  }

  for (int i = t; i < N_; i += WG) matched_g[i] = (node_min[i] == 0u) ? 1 : 0;
}

// ---------- fused per-block sums: blocks [0,nbc) -> csum, [nbc,nbc+nbn) -> nsum ----------
__global__ __launch_bounds__(CB) void k_sums(const u8* __restrict__ chosen, u32* __restrict__ csum, int E_,
                                             const u8* __restrict__ matched, u32* __restrict__ nsum, int N_,
                                             int nbc)
{
  __shared__ u32 sh[CB];
  int t = threadIdx.x, b = blockIdx.x;
  const u8* src; int n; u32* dst; int bb;
  if (b < nbc) { src = chosen; n = E_; dst = csum; bb = b; }
  else         { src = matched; n = N_; dst = nsum; bb = b - nbc; }
  int lo = bb * CCHUNK + t * CEPT;
  int hi = lo + CEPT; if (hi > n) hi = n;
  u32 c = 0;
  if (b < nbc) { for (int i = lo; i < hi; ++i) c += src[i]; }
  else         { for (int i = lo; i < hi; ++i) c += (src[i] ? 0u : 1u); }
  sh[t] = c; __syncthreads();
  for (int off = CB / 2; off > 0; off >>= 1) { if (t < off) sh[t] += sh[t + off]; __syncthreads(); }
  if (t == 0) dst[bb] = sh[0];
}

// ---------- fused assignment (csum/nsum prefixes self-computed) ----------
__global__ __launch_bounds__(CB) void k_assign(const u8* __restrict__ chosen, const u32* __restrict__ csum,
    const u32* __restrict__ pairByRank, const float* __restrict__ scoreByRank, int E_,
    const u8* __restrict__ matched, const u32* __restrict__ nsum, int N_,
    u32* __restrict__ cnts,
    int* __restrict__ cluster, u32* __restrict__ pairA, u32* __restrict__ pairB,
    float* __restrict__ cscore, int nbc, int nbn)
{
  __shared__ u32 sh[CB];
  __shared__ u32 s_off;
  int t = threadIdx.x, b = blockIdx.x;
  if (b < nbc) {
    sh[t] = (t < b) ? csum[t] : 0u;
    __syncthreads();
    for (int off = CB / 2; off > 0; off >>= 1) { if (t < off) sh[t] += sh[t + off]; __syncthreads(); }
    if (t == 0) s_off = sh[0];
    __syncthreads();
    int lo = b * CCHUNK + t * CEPT;
    int hi = lo + CEPT; if (hi > E_) hi = E_;
    u32 c = 0;
    for (int i = lo; i < hi; ++i) c += chosen[i];
    u32 mine = c;
    sh[t] = c; __syncthreads();
    for (int off = 1; off < CB; off <<= 1) {
      u32 a = (t >= off) ? sh[t - off] : 0u; __syncthreads();
      sh[t] += a; __syncthreads();
    }
    u32 run = s_off + sh[t] - mine;
    for (int i = lo; i < hi; ++i) {
      if (chosen[i]) {
        u32 cc = run++;
        u32 sd = pairByRank[i];
        u32 sv = sd >> 16, dv = sd & 0xFFFFu;
        cluster[sv] = (int)cc; cluster[dv] = (int)cc;
        pairA[cc] = sv; pairB[cc] = dv; cscore[cc] = scoreByRank[i];
      }
    }
  } else {
    int bb = b - nbc;
    sh[t] = ((t < nbc) ? csum[t] : 0u) + ((t >= nbc && t < nbc + bb) ? nsum[t - nbc] : 0u);
    __syncthreads();
    for (int off = CB / 2; off > 0; off >>= 1) { if (t < off) sh[t] += sh[t + off]; __syncthreads(); }
    if (t == 0) s_off = sh[0];
    __syncthreads();
    if (bb == 0) {   // this block also publishes num_clusters for k_out
      sh[t] = ((t < nbc) ? csum[t] : 0u) + ((t >= nbc && t < nbc + nbn) ? nsum[t - nbc] : 0u);
      __syncthreads();
      for (int off = CB / 2; off > 0; off >>= 1) { if (t < off) sh[t] += sh[t + off]; __syncthreads(); }
      if (t == 0) cnts[3] = sh[0];
      __syncthreads();
    }
    int lo = bb * CCHUNK + t * CEPT;
    int hi = lo + CEPT; if (hi > N_) hi = N_;
    u32 c = 0;
    for (int i = lo; i < hi; ++i) c += (matched[i] ? 0u : 1u);
    u32 mine = c;
    sh[t] = c; __syncthreads();
    for (int off = 1; off < CB; off <<= 1) {
      u32 a = (t >= off) ? sh[t - off] : 0u; __syncthreads();
      sh[t] += a; __syncthreads();
    }
    u32 run = s_off + sh[t] - mine;
    for (int v = lo; v < hi; ++v) {
      if (!matched[v]) {
        u32 cc = run++;
        cluster[v] = (int)cc;
        pairA[cc] = (u32)v; pairB[cc] = (u32)v; cscore[cc] = 1.0f;
      }
    }
  }
}

// ---------- fused outputs: blocks [0,nxb) -> new_x rows, [nxb,..) -> new_ei/new_batch ----------
__global__ __launch_bounds__(256) void k_out(const float* __restrict__ x, const u32* __restrict__ pairA,
                     const u32* __restrict__ pairB, const float* __restrict__ cscore,
                     const u32* __restrict__ cnts,
                     const int* __restrict__ ei, const int* __restrict__ cluster,
                     float* __restrict__ out, int N_, int E_, int nxb)
{
  int b = blockIdx.x, t = threadIdx.x;
  if (b < nxb) {
    int j = b * 256 + t;
    int total = N_ * (FDIM / 4);
    if (j >= total) return;
    u32 c = (u32)(j >> 5);
    int q = (j & 31) * 4;
    float4 o;
    if (c >= cnts[3]) {
      o.x = 0.f; o.y = 0.f; o.z = 0.f; o.w = 0.f;
    } else {
      u32 a = pairA[c], bb = pairB[c];
      float cs = cscore[c];
      const float4 va = *(const float4*)(x + (size_t)a * FDIM + q);
      if (a == bb) {
        o.x = __fmul_rn(va.x, cs); o.y = __fmul_rn(va.y, cs);
        o.z = __fmul_rn(va.z, cs); o.w = __fmul_rn(va.w, cs);
      } else {
        const float4 vb = *(const float4*)(x + (size_t)bb * FDIM + q);
        o.x = __fmul_rn(__fadd_rn(va.x, vb.x), cs);
        o.y = __fmul_rn(__fadd_rn(va.y, vb.y), cs);
        o.z = __fmul_rn(__fadd_rn(va.z, vb.z), cs);
        o.w = __fmul_rn(__fadd_rn(va.w, vb.w), cs);
      }
    }
    *(float4*)(out + (size_t)c * FDIM + q) = o;
  } else {
    int e = (b - nxb) * 256 + t;
    if (e >= E_) return;
    int c0 = cluster[ei[e]];
    int c1 = cluster[ei[E_ + e]];
    if (c0 == c1) { c0 = -1; c1 = -1; }
    size_t base = (size_t)N_ * FDIM;
    out[base + e] = (float)c0;
    out[base + E_ + e] = (float)c1;
    if (e < N_) out[base + 2 * (size_t)E_ + e] = 0.0f;              // new_batch = 0
    if (e == 0) out[base + 2 * (size_t)E_ + N_] = (float)cnts[3];   // num_clusters
  }
}

extern "C" void kernel_launch(void* const* d_in, const int* in_sizes, int n_in,
                              void* d_out, int out_size, void* d_ws, size_t ws_size,
                              hipStream_t stream)
{
  const float* x    = (const float*)d_in[0];
  const int*   ei   = (const int*)d_in[1];
  const float* wsrc = (const float*)d_in[3];
  const float* wdst = (const float*)d_in[4];
  const float* b    = (const float*)d_in[5];
  const int N = in_sizes[0] / FDIM;
  const int E = in_sizes[1] / 2;

  // workspace layout (u32 words); u64 arrays at even word offsets
  u32* w = (u32*)d_ws;
  float* raw   = (float*)w;      w += E;
  float* score = (float*)w;      w += E;
  u64* kvA = (u64*)w;            w += 2 * E;
  u64* kvB = (u64*)w;            w += 2 * E;
  float* ds = (float*)w;         w += N;
  float* dd = (float*)w;         w += N;
  int* cluster = (int*)w;        w += N;
  u32* pairA = w;                w += N;
  u32* pairB = w;                w += N;
  float* cscore = (float*)w;     w += N;
  u32* nmin = w;                 w += N;    // init in k_dots
  u32* m_enc = w;                w += N;    // init in k_dots
  u32* csum = w;                 w += 256;
  u32* nsum = w;                 w += 64;
  u32* hist = w;                 w += HST;  // no zeroing needed (columns fully stored)
  // ---- contiguous zero block (one small memset) ----
  u32* zeros = w;
  u8*  matched_g = (u8*)w;       w += (N + 3) / 4;
  u32* cnts = w;                 w += 16;
  u32* dt_d0 = w;                w += 256;  // per-pass digit totals
  u32* dt_d1 = w;                w += 256;
  u32* dt_s0 = w;                w += 256;
  u32* dt_s1 = w;                w += 256;
  u32* dt_s2 = w;                w += 256;
  size_t zwords = (size_t)(w - zeros);

  // d_out doubles as scratch (fully overwritten by outputs at the end)
  u64* liveA = (u64*)d_out;                                  // 2E u32 words
  u64* liveB = (u64*)((u32*)d_out + 2 * (size_t)E);          // 2E words
  u32* pairByRank  = (u32*)d_out + 4 * (size_t)E;            // E words
  float* scoreByRank = (float*)((u32*)d_out + 5 * (size_t)E);// E words
  u8* chosen = (u8*)((u32*)d_out + 6 * (size_t)E);           // E bytes

  const int TB = 256;
  const int gridE = (E + TB - 1) / TB;
  const int gridN = (N + TB - 1) / TB;
  const int nb = (E + RCHUNK - 1) / RCHUNK;     // ~196, <= 200
  const int nbc = (E + CCHUNK - 1) / CCHUNK;    // <= 200
  const int nbn = (N + CCHUNK - 1) / CCHUNK;    // ~25 (nbc + nbn <= 256)
  const int nxb = (N * (FDIM / 4) + TB - 1) / TB;

  hipMemsetAsync(zeros, 0, zwords * 4, stream);

  // dots (+ nmin/m_enc init) -> per-edge raw + dst keys (pass0 hist + dtot fused)
  k_dots<<<gridN, TB, 0, stream>>>(x, wsrc, wdst, ds, dd, nmin, m_enc, N);
  k_rawE<<<nb, RB, 0, stream>>>(ei, ds, dd, b, raw, m_enc, kvA, hist, dt_d0, nb, E);

  // dst sort: 2x 8-bit passes, A->B->A (keys < 2^15)
  k_rbase<<<256, 256, 0, stream>>>(hist, dt_d0, nb);
  k_rscat<<<nb, RB, 0, stream>>>(kvA, kvB, hist, E, nb, 0);
  k_rhist<<<nb, RB, 0, stream>>>(kvB, hist, dt_d1, E, nb, 8);
  k_rbase<<<256, 256, 0, stream>>>(hist, dt_d1, nb);
  k_rscat<<<nb, RB, 0, stream>>>(kvB, kvA, hist, E, nb, 8);

  // scores from dst-sorted segments (denominator in edge-id order)
  k_scores_seg<<<gridE, TB, 0, stream>>>(kvA, raw, m_enc, score, E);

  // score sort: 3x 8-bit passes (top byte constant), B->A->B, final scatter fused w/ prep
  k_key_score<<<nb, RB, 0, stream>>>(score, ei, kvB, hist, dt_s0, nb, E);
  k_rbase<<<256, 256, 0, stream>>>(hist, dt_s0, nb);
  k_rscat<<<nb, RB, 0, stream>>>(kvB, kvA, hist, E, nb, 0);
  k_rhist<<<nb, RB, 0, stream>>>(kvA, hist, dt_s1, E, nb, 8);
  k_rbase<<<256, 256, 0, stream>>>(hist, dt_s1, nb);
  k_rscat<<<nb, RB, 0, stream>>>(kvA, kvB, hist, E, nb, 8);
  k_rhist<<<nb, RB, 0, stream>>>(kvB, hist, dt_s2, E, nb, 16);
  k_rbase<<<256, 256, 0, stream>>>(hist, dt_s2, nb);
  k_rscatP<<<nb, RB, 0, stream>>>(kvB, hist, E, nb, 16,
                                  pairByRank, scoreByRank, chosen, nmin);

  // eager pre-round 0: per-node choose (complete nmin), then compact (complete matched_g)
  k_choose0N<<<gridN, TB, 0, stream>>>(pairByRank, nmin, chosen, matched_g, N);
  k_compact0<<<gridE, TB, 0, stream>>>(pairByRank, matched_g, liveB, nmin, &cnts[8], E);

  // eager pre-rounds 1..PRROUNDS-1: ping-pong starting from liveB
  u64* Lin = liveB; u64* Lout = liveA;
  for (int r = 1; r < PRROUNDS; ++r) {
    k_chooseR<<<gridE, TB, 0, stream>>>(Lin, &cnts[8 + r - 1], nmin, chosen, matched_g, TAG(r));
    k_compactR<<<gridE, TB, 0, stream>>>(Lin, &cnts[8 + r - 1], matched_g, Lout, nmin,
                                         &cnts[8 + r], TAG(r + 1));
    u64* tmp = Lin; Lin = Lout; Lout = tmp;
  }
  // Lin holds round-(PRROUNDS-1) survivors (tracked pointers, r4-bug lesson)

  // residual rounds (single block)
  k_match<<<1, WG, 0, stream>>>(Lin, Lout, nmin, matched_g, &cnts[8 + PRROUNDS - 1],
                                chosen, N);

  // cluster-id assignment (block sums + self-prefixing assign)
  k_sums<<<nbc + nbn, CB, 0, stream>>>(chosen, csum, E, matched_g, nsum, N, nbc);
  k_assign<<<nbc + nbn, CB, 0, stream>>>(chosen, csum, pairByRank, scoreByRank, E,
                                         matched_g, nsum, N, cnts,
                                         cluster, pairA, pairB, cscore, nbc, nbn);

  // fused outputs (fully overwrite d_out; scratch regions dead by now)
  k_out<<<nxb + gridE, TB, 0, stream>>>(x, pairA, pairB, cscore, cnts, ei, cluster,
                                        (float*)d_out, N, E, nxb);
}

// Round 15
// 335.840 us; speedup vs baseline: 1.0218x; 1.0218x over previous
//
#include <hip/hip_runtime.h>
#include <stdint.h>

typedef unsigned int u32;
typedef unsigned long long u64;
typedef unsigned short u16;
typedef unsigned char u8;

#define FDIM  128
#define NNODE 25000   // LDS sizing; N <= this
#define WG    1024
#define RB    64      // radix block threads (1 wave)
#define EPT   16      // radix elements per thread
#define RCHUNK (RB*EPT) // 1024 elements per radix block -> nb ~ 196 blocks
// rank fits 18 bits (E <= 262143); round tag in upper 14 bits, decreasing per round
#define KBITS 18
#define RMASK ((1u << KBITS) - 1u)
#define TAG(r) (((0x3FFFu - (u32)(r)) << KBITS))
#define PRROUNDS 4      // eager rounds 0..3 multi-block; k_match starts at round 4
#define CB 256
#define CEPT 4
#define CCHUNK (CB*CEPT)
#define HST (256*200)   // one shared hist buffer [256][nb], nb <= 200
#define SCCH 1024       // multi-block scan chunk (words)

// ---------- monotone float<->uint encoding (order-preserving, bijective) ----------
__device__ __forceinline__ u32 enc_f32(float f){
  u32 u = __float_as_uint(f);
  return (u & 0x80000000u) ? ~u : (u | 0x80000000u);
}
__device__ __forceinline__ float dec_f32(u32 u){
  u = (u & 0x80000000u) ? (u ^ 0x80000000u) : ~u;
  return __uint_as_float(u);
}
// NOTE (r11 lesson): filtered atomics (volatile pre-read + conditional atomic) FORCE
// uncached coherence-point reads -> 7MB FETCH and +21us in k_compact0. Plain
// fire-and-forget atomicMin/Max is latency-hidden. Do NOT "filter" atomics here.

// ---------- XLA CPU GenerateVF32Exp replica (DO NOT TOUCH - validated r1) ----------
__device__ __forceinline__ float xla_expf(float x){
  x = fminf(x,  88.3762626647950f);
  x = fmaxf(x, -88.3762626647949f);
  float fx = floorf(fmaf(x, 1.44269504088896341f, 0.5f));
  float tmp = __fmul_rn(fx, 0.693359375f);
  float zz  = __fmul_rn(fx, -2.12194440e-4f);
  x = __fsub_rn(x, tmp);
  x = __fsub_rn(x, zz);
  float z2 = __fmul_rn(x, x);
  float y = fmaf(1.9875691500E-4f, x, 1.3981999507E-3f);
  y = fmaf(y, x, 8.3334519073E-3f);
  y = fmaf(y, x, 4.1665795894E-2f);
  y = fmaf(y, x, 1.6666665459E-1f);
  y = fmaf(y, x, 5.0000001201E-1f);
  y = fmaf(y, z2, x);
  y = __fadd_rn(y, 1.0f);
  int n = (int)fx;
  float p2n = __uint_as_float((u32)(n + 127) << 23);
  return __fmul_rn(y, p2n);
}

// ---------- per-node dots (bit-identical sequential unfused order) + nmin/m_enc init ----------
__global__ __launch_bounds__(256) void k_dots(const float* __restrict__ x,
                      const float* __restrict__ wsrc, const float* __restrict__ wdst,
                      float* __restrict__ ds, float* __restrict__ dd,
                      u32* __restrict__ nmin, u32* __restrict__ m_enc, int N_)
{
  __shared__ float4 w4[64];
  int t = threadIdx.x;
  if (t < 32) w4[t] = ((const float4*)wsrc)[t];
  else if (t < 64) w4[t] = ((const float4*)wdst)[t - 32];
  __syncthreads();
  int v = blockIdx.x * blockDim.x + t;
  if (v >= N_) return;
  nmin[v] = 0xFFFFFFFFu;   // replaces 0xFF memset (consumed first by k_rscatP)
  m_enc[v] = 0u;           // replaces zero memset (consumed first by k_rawE)
  const float4* xr = (const float4*)(x + (size_t)v * FDIM);
  float accs = 0.f, accd = 0.f;
  #pragma unroll 4
  for (int k = 0; k < 32; ++k) {
    float4 xv = xr[k], w = w4[k], u = w4[k + 32];
    accs = __fadd_rn(accs, __fmul_rn(xv.x, w.x));
    accs = __fadd_rn(accs, __fmul_rn(xv.y, w.y));
    accs = __fadd_rn(accs, __fmul_rn(xv.z, w.z));
    accs = __fadd_rn(accs, __fmul_rn(xv.w, w.w));
    accd = __fadd_rn(accd, __fmul_rn(xv.x, u.x));
    accd = __fadd_rn(accd, __fmul_rn(xv.y, u.y));
    accd = __fadd_rn(accd, __fmul_rn(xv.z, u.z));
    accd = __fadd_rn(accd, __fmul_rn(xv.w, u.w));
  }
  ds[v] = accs; dd[v] = accd;
}

// ---------- per-edge raw + dst max + dst-sort keys + pass0 hist (LDS, col store) ----------
__global__ __launch_bounds__(RB) void k_rawE(const int* __restrict__ ei, const float* __restrict__ ds,
                       const float* __restrict__ dd, const float* __restrict__ bia,
                       float* __restrict__ raw, u32* __restrict__ m_enc,
                       u64* __restrict__ kvA, u32* __restrict__ hist, int nb, int E_)
{
  __shared__ u32 h[256];
  int t = threadIdx.x, b = blockIdx.x;
  for (int i = t; i < 256; i += RB) h[i] = 0;
  __syncthreads();
  int lo = b * RCHUNK + t * EPT;
  int hi = lo + EPT; if (hi > E_) hi = E_;
  float bv = bia[0];
  for (int e = lo; e < hi; ++e) {
    int s = ei[e], d = ei[E_ + e];
    float r = __fadd_rn(__fadd_rn(ds[s], dd[d]), bv);
    raw[e] = r;
    atomicMax(&m_enc[d], enc_f32(r));
    kvA[e] = ((u64)(u32)d << 32) | (u32)e;
    atomicAdd(&h[(u32)d & 255u], 1u);
  }
  __syncthreads();
  for (int i = t; i < 256; i += RB) hist[(size_t)i * nb + b] = h[i];
}

// ---------- radix: hist of one 8-bit digit (LDS aggregated, plain col store) ----------
__global__ __launch_bounds__(RB) void k_rhist(const u64* __restrict__ kv, u32* __restrict__ hist,
                                              int n, int nb, int shift)
{
  __shared__ u32 h[256];
  int t = threadIdx.x, b = blockIdx.x;
  for (int i = t; i < 256; i += RB) h[i] = 0;
  __syncthreads();
  int lo = b * RCHUNK + t * EPT;
  int hi = lo + EPT; if (hi > n) hi = n;
  for (int i = lo; i < hi; ++i) atomicAdd(&h[((u32)(kv[i] >> 32) >> shift) & 255u], 1u);
  __syncthreads();
  for (int i = t; i < 256; i += RB) hist[(size_t)i * nb + b] = h[i];
}

// ---------- multi-block exclusive scan of hist [256][nb] (2 dispatches; r13 form) ----------
__global__ __launch_bounds__(256) void k_mbs1(const u32* __restrict__ a, u32* __restrict__ bsum, int m)
{
  __shared__ u32 sh[256];
  int t = threadIdx.x, b = blockIdx.x;
  int base = b * SCCH;
  u32 s = 0;
  #pragma unroll
  for (int k = 0; k < SCCH / 256; ++k) { int i = base + t + k * 256; if (i < m) s += a[i]; }
  sh[t] = s; __syncthreads();
  for (int off = 128; off > 0; off >>= 1) { if (t < off) sh[t] += sh[t + off]; __syncthreads(); }
  if (t == 0) bsum[b] = sh[0];
}

__global__ __launch_bounds__(256) void k_mbs3(u32* __restrict__ a, const u32* __restrict__ bsum, int m)
{
  __shared__ u32 sh[256];
  __shared__ u32 s_off;
  const int W = SCCH / 256;   // words per thread (consecutive)
  int t = threadIdx.x, b = blockIdx.x;
  sh[t] = (t < b) ? bsum[t] : 0u;
  __syncthreads();
  for (int off = 128; off > 0; off >>= 1) { if (t < off) sh[t] += sh[t + off]; __syncthreads(); }
  if (t == 0) s_off = sh[0];
  __syncthreads();
  int lo = b * SCCH + t * W;
  u32 v[W];
  u32 c = 0;
  #pragma unroll
  for (int k = 0; k < W; ++k) { int i = lo + k; v[k] = (i < m) ? a[i] : 0u; c += v[k]; }
  u32 mine = c;
  sh[t] = c; __syncthreads();
  for (int off = 1; off < 256; off <<= 1) {
    u32 x = (t >= off) ? sh[t - off] : 0u; __syncthreads();
    sh[t] += x; __syncthreads();
  }
  u32 run = s_off + sh[t] - mine;
  #pragma unroll
  for (int k = 0; k < W; ++k) { int i = lo + k; if (i < m) { a[i] = run; run += v[k]; } }
}

// ---------- radix: stable scatter of u64 kv (key = high32) ----------
__global__ __launch_bounds__(RB) void k_rscat(const u64* __restrict__ kvin, u64* __restrict__ kvout,
                                              const u32* __restrict__ base, int n, int nb, int shift)
{
  __shared__ u16 h[RB][258];
  __shared__ u32 gbase[256];
  int t = threadIdx.x, b = blockIdx.x;
  for (int i = t; i < RB * 258 / 2; i += RB) ((u32*)h)[i] = 0u;
  __syncthreads();
  int lo = b * RCHUNK + t * EPT;
  int hi = lo + EPT; if (hi > n) hi = n;
  for (int i = lo; i < hi; ++i) { u32 d = ((u32)(kvin[i] >> 32) >> shift) & 255u; h[t][d]++; }
  __syncthreads();
  for (int dg = t; dg < 256; dg += RB) {   // each thread owns 4 digits
    u32 run = 0;
    for (int q = 0; q < RB; ++q) { u16 c = h[q][dg]; h[q][dg] = (u16)run; run += c; }
    gbase[dg] = base[(size_t)dg * nb + b];
  }
  __syncthreads();
  for (int i = lo; i < hi; ++i) {
    u64 kv = kvin[i];
    u32 d = ((u32)(kv >> 32) >> shift) & 255u;
    u32 p = gbase[d] + (u32)h[t][d];
    h[t][d]++;
    kvout[p] = kv;
  }
}

// ---------- final score-scatter fused with prep: per-rank metadata + round-0 mins ----------
__global__ __launch_bounds__(RB) void k_rscatP(const u64* __restrict__ kvin,
                                               const u32* __restrict__ base, int n, int nb, int shift,
                                               u32* __restrict__ pairByRank, float* __restrict__ scoreByRank,
                                               u8* __restrict__ chosen, u32* __restrict__ nmin)
{
  __shared__ u16 h[RB][258];
  __shared__ u32 gbase[256];
  int t = threadIdx.x, b = blockIdx.x;
  for (int i = t; i < RB * 258 / 2; i += RB) ((u32*)h)[i] = 0u;
  __syncthreads();
  int lo = b * RCHUNK + t * EPT;
  int hi = lo + EPT; if (hi > n) hi = n;
  for (int i = lo; i < hi; ++i) { u32 d = ((u32)(kvin[i] >> 32) >> shift) & 255u; h[t][d]++; }
  __syncthreads();
  for (int dg = t; dg < 256; dg += RB) {
    u32 run = 0;
    for (int q = 0; q < RB; ++q) { u16 c = h[q][dg]; h[q][dg] = (u16)run; run += c; }
    gbase[dg] = base[(size_t)dg * nb + b];
  }
  __syncthreads();
  for (int i = lo; i < hi; ++i) {
    u64 kv = kvin[i];
    u32 key = (u32)(kv >> 32);
    u32 d = (key >> shift) & 255u;
    u32 p = gbase[d] + (u32)h[t][d];
    h[t][d]++;
    u32 sd = (u32)kv;
    pairByRank[p] = sd;
    scoreByRank[p] = dec_f32(~key);   // enc bijective -> exact score bits
    chosen[p] = 0;
    u32 val = TAG(0) | p;
    atomicMin(&nmin[sd >> 16], val);
    atomicMin(&nmin[sd & 0xFFFFu], val);
  }
}

// ---------- softmax scores from dst-sorted kv segments (edge-id order in segment) ----------
__global__ void k_scores_seg(const u64* __restrict__ kvS, const float* __restrict__ raw,
                             const u32* __restrict__ m_enc, float* __restrict__ score, int E_)
{
  int i = blockIdx.x * blockDim.x + threadIdx.x;
  if (i >= E_) return;
  u32 d = (u32)(kvS[i] >> 32);
  if (i > 0 && (u32)(kvS[i - 1] >> 32) == d) return;   // not a segment head
  float m = dec_f32(m_enc[d]);
  float denom = 0.f;
  int j = i;
  while (j < E_) {
    u64 kv = kvS[j];
    if ((u32)(kv >> 32) != d) break;
    denom = __fadd_rn(denom, xla_expf(__fsub_rn(raw[(u32)kv], m)));
    ++j;
  }
  for (int q = i; q < j; ++q) {
    u32 e = (u32)kvS[q];
    float z = xla_expf(__fsub_rn(raw[e], m));
    score[e] = __fadd_rn(__fdiv_rn(z, denom), 0.5f);
  }
}

// ---------- score-sort keys + pass0 hist (LDS, col store) ----------
__global__ __launch_bounds__(RB) void k_key_score(const float* __restrict__ score, const int* __restrict__ ei,
                            u64* __restrict__ kvB, u32* __restrict__ hist, int nb, int E_)
{
  __shared__ u32 h[256];
  int t = threadIdx.x, b = blockIdx.x;
  for (int i = t; i < 256; i += RB) h[i] = 0;
  __syncthreads();
  int lo = b * RCHUNK + t * EPT;
  int hi = lo + EPT; if (hi > E_) hi = E_;
  for (int e = lo; e < hi; ++e) {
    u32 key = ~enc_f32(score[e]);   // ascending => descending score; stable => id asc
    u32 sd = ((u32)ei[e] << 16) | (u32)ei[E_ + e];
    kvB[e] = ((u64)key << 32) | sd;
    atomicAdd(&h[key & 255u], 1u);
  }
  __syncthreads();
  for (int i = t; i < 256; i += RB) hist[(size_t)i * nb + b] = h[i];
}

// ---------- eager round 0 choose, PER-NODE (r12) ----------
__global__ void k_choose0N(const u32* __restrict__ pairByRank, const u32* __restrict__ nmin,
                           u8* __restrict__ chosen, u8* __restrict__ matched_g, int N_)
{
  int v = blockIdx.x * blockDim.x + threadIdx.x;
  if (v >= N_) return;
  u32 mv = nmin[v];
  if (mv == 0xFFFFFFFFu) return;         // no incident edge
  u32 k = mv & RMASK;
  u32 sd = pairByRank[k];
  u32 s = sd >> 16, d = sd & 0xFFFFu;
  u32 other = ((u32)v == s) ? d : s;
  if (nmin[other] == mv) {
    matched_g[v] = 1;
    if ((u32)v == s) chosen[k] = 1;
  }
}

__global__ void k_compact0(const u32* __restrict__ pairByRank, const u8* __restrict__ matched_g,
                           u64* __restrict__ liveOut, u32* __restrict__ nmin,
                           u32* __restrict__ nlive, int E_)
{
  int k = blockIdx.x * blockDim.x + threadIdx.x;
  int lane = threadIdx.x & 63;
  bool liveE = false; u32 s = 0, d = 0;
  if (k < E_) {
    u32 sd = pairByRank[k];
    s = sd >> 16; d = sd & 0xFFFFu;
    liveE = (!matched_g[s] && !matched_g[d]);
  }
  u64 m = __ballot(liveE);
  if (m != 0ull) {
    int leader = __ffsll((long long)m) - 1;
    u32 base = 0;
    if (lane == leader) base = atomicAdd(nlive, (u32)__popcll(m));
    base = (u32)__shfl((int)base, leader);
    if (liveE) {
      u32 pfx = (u32)__popcll(m & ((1ull << lane) - 1ull));
      liveOut[base + pfx] = ((u64)(u32)k << 32) | ((u64)s << 16) | (u64)d;
      u32 nval = TAG(1) | (u32)k;
      atomicMin(&nmin[s], nval);
      atomicMin(&nmin[d], nval);
    }
  }
}

// ---------- eager pre-round r >= 1 ----------
__global__ void k_chooseR(const u64* __restrict__ liveIn, const u32* __restrict__ nliveIn,
                          const u32* __restrict__ nmin,
                          u8* __restrict__ chosen, u8* __restrict__ matched_g, u32 rtag)
{
  u32 i = blockIdx.x * blockDim.x + threadIdx.x;
  if (i >= *nliveIn) return;
  u64 v = liveIn[i];
  u32 k = (u32)(v >> 32), s = ((u32)v) >> 16, d = (u32)v & 0xFFFFu;
  u32 myval = rtag | k;
  if (nmin[s] == myval && nmin[d] == myval) { chosen[k] = 1; matched_g[s] = 1; matched_g[d] = 1; }
}

__global__ void k_compactR(const u64* __restrict__ liveIn, const u32* __restrict__ nliveIn,
                           const u8* __restrict__ matched_g,
                           u64* __restrict__ liveOut, u32* __restrict__ nmin,
                           u32* __restrict__ nliveOut, u32 ntag)
{
  u32 i = blockIdx.x * blockDim.x + threadIdx.x;
  int lane = threadIdx.x & 63;
  bool liveE = false; u64 v = 0; u32 s = 0, d = 0;
  if (i < *nliveIn) {
    v = liveIn[i];
    s = ((u32)v) >> 16; d = (u32)v & 0xFFFFu;
    liveE = (!matched_g[s] && !matched_g[d]);
  }
  u64 m = __ballot(liveE);
  if (m != 0ull) {
    int leader = __ffsll((long long)m) - 1;
    u32 base = 0;
    if (lane == leader) base = atomicAdd(nliveOut, (u32)__popcll(m));
    base = (u32)__shfl((int)base, leader);
    if (liveE) {
      u32 pfx = (u32)__popcll(m & ((1ull << lane) - 1ull));
      liveOut[base + pfx] = v;
      u32 nval = ntag | (u32)(v >> 32);
      atomicMin(&nmin[s], nval);
      atomicMin(&nmin[d], nval);
    }
  }
}

// ---------- single-block residual fixpoint (rounds >= PRROUNDS) ----------
__global__ __launch_bounds__(WG) void k_match(
    u64* liveA, u64* liveB, const u32* __restrict__ nmin_g, u8* __restrict__ matched_g,
    const u32* __restrict__ nliveIn, u8* __restrict__ chosen, int N_)
{
  __shared__ u32 node_min[NNODE];
  __shared__ u32 s_nlive, s_next;
  const int t = threadIdx.x;
  const int lane = t & 63;

  for (int i = t; i < N_; i += WG) node_min[i] = matched_g[i] ? 0u : nmin_g[i];
  if (t == 0) { s_nlive = *nliveIn; s_next = 0u; }
  __syncthreads();

  u64* LA = liveA; u64* LB = liveB;
  u32 r = PRROUNDS;
  while (true) {
    u32 nl = s_nlive;
    if (nl == 0u || r > 16000u) break;
    const u32 tag  = TAG(r);
    const u32 ntag = TAG(r + 1);

    for (u32 i = (u32)t; i < nl; i += WG) {
      u64 v = LA[i];
      u32 k = (u32)(v >> 32);
      u32 s = ((u32)v) >> 16, d = (u32)v & 0xFFFFu;
      u32 myval = tag | k;
      if (node_min[s] == myval && node_min[d] == myval) {
        chosen[k] = 1; node_min[s] = 0u; node_min[d] = 0u;
      }
    }
    __syncthreads();

    for (u32 i0 = (u32)(t & ~63); i0 < nl; i0 += WG) {
      u32 i = i0 + (u32)lane;
      bool liveE = false; u64 v = 0;
      u32 s = 0, d = 0;
      if (i < nl) {
        v = LA[i];
        s = ((u32)v) >> 16; d = (u32)v & 0xFFFFu;
        liveE = (node_min[s] != 0u && node_min[d] != 0u);
      }
      u64 m = __ballot(liveE);
      if (m != 0ull) {
        int leader = __ffsll((long long)m) - 1;
        u32 baseIdx = 0;
        if (lane == leader) baseIdx = atomicAdd(&s_next, (u32)__popcll(m));
        baseIdx = (u32)__shfl((int)baseIdx, leader);
        if (liveE) {
          u32 pfx = (u32)__popcll(m & ((1ull << lane) - 1ull));
          LB[baseIdx + pfx] = v;
          u32 nval = ntag | (u32)(v >> 32);
          atomicMin(&node_min[s], nval);
          atomicMin(&node_min[d], nval);
        }
      }
    }
    __syncthreads();
    if (t == 0) { s_nlive = s_next; s_next = 0u; }
    { u64* tmp = LA; LA = LB; LB = tmp; }
    ++r;
    __syncthreads();
  }

  for (int i = t; i < N_; i += WG) matched_g[i] = (node_min[i] == 0u) ? 1 : 0;
}

// ---------- fused per-block sums: blocks [0,nbc) -> csum, [nbc,nbc+nbn) -> nsum ----------
__global__ __launch_bounds__(CB) void k_sums(const u8* __restrict__ chosen, u32* __restrict__ csum, int E_,
                                             const u8* __restrict__ matched, u32* __restrict__ nsum, int N_,
                                             int nbc)
{
  __shared__ u32 sh[CB];
  int t = threadIdx.x, b = blockIdx.x;
  const u8* src; int n; u32* dst; int bb;
  if (b < nbc) { src = chosen; n = E_; dst = csum; bb = b; }
  else         { src = matched; n = N_; dst = nsum; bb = b - nbc; }
  int lo = bb * CCHUNK + t * CEPT;
  int hi = lo + CEPT; if (hi > n) hi = n;
  u32 c = 0;
  if (b < nbc) { for (int i = lo; i < hi; ++i) c += src[i]; }
  else         { for (int i = lo; i < hi; ++i) c += (src[i] ? 0u : 1u); }
  sh[t] = c; __syncthreads();
  for (int off = CB / 2; off > 0; off >>= 1) { if (t < off) sh[t] += sh[t + off]; __syncthreads(); }
  if (t == 0) dst[bb] = sh[0];
}

// ---------- fused assignment (csum/nsum prefixes self-computed) ----------
__global__ __launch_bounds__(CB) void k_assign(const u8* __restrict__ chosen, const u32* __restrict__ csum,
    const u32* __restrict__ pairByRank, const float* __restrict__ scoreByRank, int E_,
    const u8* __restrict__ matched, const u32* __restrict__ nsum, int N_,
    u32* __restrict__ cnts,
    int* __restrict__ cluster, u32* __restrict__ pairA, u32* __restrict__ pairB,
    float* __restrict__ cscore, int nbc, int nbn)
{
  __shared__ u32 sh[CB];
  __shared__ u32 s_off;
  int t = threadIdx.x, b = blockIdx.x;
  if (b < nbc) {
    sh[t] = (t < b) ? csum[t] : 0u;
    __syncthreads();
    for (int off = CB / 2; off > 0; off >>= 1) { if (t < off) sh[t] += sh[t + off]; __syncthreads(); }
    if (t == 0) s_off = sh[0];
    __syncthreads();
    int lo = b * CCHUNK + t * CEPT;
    int hi = lo + CEPT; if (hi > E_) hi = E_;
    u32 c = 0;
    for (int i = lo; i < hi; ++i) c += chosen[i];
    u32 mine = c;
    sh[t] = c; __syncthreads();
    for (int off = 1; off < CB; off <<= 1) {
      u32 a = (t >= off) ? sh[t - off] : 0u; __syncthreads();
      sh[t] += a; __syncthreads();
    }
    u32 run = s_off + sh[t] - mine;
    for (int i = lo; i < hi; ++i) {
      if (chosen[i]) {
        u32 cc = run++;
        u32 sd = pairByRank[i];
        u32 sv = sd >> 16, dv = sd & 0xFFFFu;
        cluster[sv] = (int)cc; cluster[dv] = (int)cc;
        pairA[cc] = sv; pairB[cc] = dv; cscore[cc] = scoreByRank[i];
      }
    }
  } else {
    int bb = b - nbc;
    sh[t] = ((t < nbc) ? csum[t] : 0u) + ((t >= nbc && t < nbc + bb) ? nsum[t - nbc] : 0u);
    __syncthreads();
    for (int off = CB / 2; off > 0; off >>= 1) { if (t < off) sh[t] += sh[t + off]; __syncthreads(); }
    if (t == 0) s_off = sh[0];
    __syncthreads();
    if (bb == 0) {   // this block also publishes num_clusters for k_out
      sh[t] = ((t < nbc) ? csum[t] : 0u) + ((t >= nbc && t < nbc + nbn) ? nsum[t - nbc] : 0u);
      __syncthreads();
      for (int off = CB / 2; off > 0; off >>= 1) { if (t < off) sh[t] += sh[t + off]; __syncthreads(); }
      if (t == 0) cnts[3] = sh[0];
      __syncthreads();
    }
    int lo = bb * CCHUNK + t * CEPT;
    int hi = lo + CEPT; if (hi > N_) hi = N_;
    u32 c = 0;
    for (int i = lo; i < hi; ++i) c += (matched[i] ? 0u : 1u);
    u32 mine = c;
    sh[t] = c; __syncthreads();
    for (int off = 1; off < CB; off <<= 1) {
      u32 a = (t >= off) ? sh[t - off] : 0u; __syncthreads();
      sh[t] += a; __syncthreads();
    }
    u32 run = s_off + sh[t] - mine;
    for (int v = lo; v < hi; ++v) {
      if (!matched[v]) {
        u32 cc = run++;
        cluster[v] = (int)cc;
        pairA[cc] = (u32)v; pairB[cc] = (u32)v; cscore[cc] = 1.0f;
      }
    }
  }
}

// ---------- fused outputs: blocks [0,nxb) -> new_x rows, [nxb,..) -> new_ei/new_batch ----------
__global__ __launch_bounds__(256) void k_out(const float* __restrict__ x, const u32* __restrict__ pairA,
                     const u32* __restrict__ pairB, const float* __restrict__ cscore,
                     const u32* __restrict__ cnts,
                     const int* __restrict__ ei, const int* __restrict__ cluster,
                     float* __restrict__ out, int N_, int E_, int nxb)
{
  int b = blockIdx.x, t = threadIdx.x;
  if (b < nxb) {
    int j = b * 256 + t;
    int total = N_ * (FDIM / 4);
    if (j >= total) return;
    u32 c = (u32)(j >> 5);
    int q = (j & 31) * 4;
    float4 o;
    if (c >= cnts[3]) {
      o.x = 0.f; o.y = 0.f; o.z = 0.f; o.w = 0.f;
    } else {
      u32 a = pairA[c], bb = pairB[c];
      float cs = cscore[c];
      const float4 va = *(const float4*)(x + (size_t)a * FDIM + q);
      if (a == bb) {
        o.x = __fmul_rn(va.x, cs); o.y = __fmul_rn(va.y, cs);
        o.z = __fmul_rn(va.z, cs); o.w = __fmul_rn(va.w, cs);
      } else {
        const float4 vb = *(const float4*)(x + (size_t)bb * FDIM + q);
        o.x = __fmul_rn(__fadd_rn(va.x, vb.x), cs);
        o.y = __fmul_rn(__fadd_rn(va.y, vb.y), cs);
        o.z = __fmul_rn(__fadd_rn(va.z, vb.z), cs);
        o.w = __fmul_rn(__fadd_rn(va.w, vb.w), cs);
      }
    }
    *(float4*)(out + (size_t)c * FDIM + q) = o;
  } else {
    int e = (b - nxb) * 256 + t;
    if (e >= E_) return;
    int c0 = cluster[ei[e]];
    int c1 = cluster[ei[E_ + e]];
    if (c0 == c1) { c0 = -1; c1 = -1; }
    size_t base = (size_t)N_ * FDIM;
    out[base + e] = (float)c0;
    out[base + E_ + e] = (float)c1;
    if (e < N_) out[base + 2 * (size_t)E_ + e] = 0.0f;              // new_batch = 0
    if (e == 0) out[base + 2 * (size_t)E_ + N_] = (float)cnts[3];   // num_clusters
  }
}

extern "C" void kernel_launch(void* const* d_in, const int* in_sizes, int n_in,
                              void* d_out, int out_size, void* d_ws, size_t ws_size,
                              hipStream_t stream)
{
  const float* x    = (const float*)d_in[0];
  const int*   ei   = (const int*)d_in[1];
  const float* wsrc = (const float*)d_in[3];
  const float* wdst = (const float*)d_in[4];
  const float* b    = (const float*)d_in[5];
  const int N = in_sizes[0] / FDIM;
  const int E = in_sizes[1] / 2;

  // workspace layout (u32 words); u64 arrays at even word offsets
  u32* w = (u32*)d_ws;
  float* raw   = (float*)w;      w += E;
  float* score = (float*)w;      w += E;
  u64* kvA = (u64*)w;            w += 2 * E;
  u64* kvB = (u64*)w;            w += 2 * E;
  float* ds = (float*)w;         w += N;
  float* dd = (float*)w;         w += N;
  int* cluster = (int*)w;        w += N;
  u32* pairA = w;                w += N;
  u32* pairB = w;                w += N;
  float* cscore = (float*)w;     w += N;
  u32* nmin = w;                 w += N;    // init in k_dots
  u32* m_enc = w;                w += N;    // init in k_dots
  u32* csum = w;                 w += 256;
  u32* nsum = w;                 w += 64;
  u32* bsum = w;                 w += 256;  // multi-block scan partials
  u32* hist = w;                 w += HST;  // no zeroing needed (columns fully stored)
  // ---- contiguous zero block (one small memset) ----
  u32* zeros = w;
  u8*  matched_g = (u8*)w;       w += (N + 3) / 4;
  u32* cnts = w;                 w += 16;
  size_t zwords = (size_t)(w - zeros);

  // d_out doubles as scratch (fully overwritten by outputs at the end)
  u64* liveA = (u64*)d_out;                                  // 2E u32 words
  u64* liveB = (u64*)((u32*)d_out + 2 * (size_t)E);          // 2E words
  u32* pairByRank  = (u32*)d_out + 4 * (size_t)E;            // E words
  float* scoreByRank = (float*)((u32*)d_out + 5 * (size_t)E);// E words
  u8* chosen = (u8*)((u32*)d_out + 6 * (size_t)E);           // E bytes

  const int TB = 256;
  const int gridE = (E + TB - 1) / TB;
  const int gridN = (N + TB - 1) / TB;
  const int nb = (E + RCHUNK - 1) / RCHUNK;     // ~196, <= 200
  const int m  = nb * 256;
  const int nsb = (m + SCCH - 1) / SCCH;        // multi-block scan blocks (~49)
  const int nbc = (E + CCHUNK - 1) / CCHUNK;    // <= 200
  const int nbn = (N + CCHUNK - 1) / CCHUNK;    // ~25 (nbc + nbn <= 256)
  const int nxb = (N * (FDIM / 4) + TB - 1) / TB;

  hipMemsetAsync(zeros, 0, zwords * 4, stream);

  // hist exclusive scan (multi-block, 2 dispatches; r13-measured-best form)
  #define HSCAN() do { \
    k_mbs1<<<nsb, 256, 0, stream>>>(hist, bsum, m); \
    k_mbs3<<<nsb, 256, 0, stream>>>(hist, bsum, m); \
  } while (0)

  // dots (+ nmin/m_enc init) -> per-edge raw + dst keys (pass0 hist fused)
  k_dots<<<gridN, TB, 0, stream>>>(x, wsrc, wdst, ds, dd, nmin, m_enc, N);
  k_rawE<<<nb, RB, 0, stream>>>(ei, ds, dd, b, raw, m_enc, kvA, hist, nb, E);

  // dst sort: 2x 8-bit passes, A->B->A (keys < 2^15)
  HSCAN();
  k_rscat<<<nb, RB, 0, stream>>>(kvA, kvB, hist, E, nb, 0);
  k_rhist<<<nb, RB, 0, stream>>>(kvB, hist, E, nb, 8);
  HSCAN();
  k_rscat<<<nb, RB, 0, stream>>>(kvB, kvA, hist, E, nb, 8);

  // scores from dst-sorted segments (denominator in edge-id order)
  k_scores_seg<<<gridE, TB, 0, stream>>>(kvA, raw, m_enc, score, E);

  // score sort: 3x 8-bit passes (top byte constant), B->A->B, final scatter fused w/ prep
  k_key_score<<<nb, RB, 0, stream>>>(score, ei, kvB, hist, nb, E);
  HSCAN();
  k_rscat<<<nb, RB, 0, stream>>>(kvB, kvA, hist, E, nb, 0);
  k_rhist<<<nb, RB, 0, stream>>>(kvA, hist, E, nb, 8);
  HSCAN();
  k_rscat<<<nb, RB, 0, stream>>>(kvA, kvB, hist, E, nb, 8);
  k_rhist<<<nb, RB, 0, stream>>>(kvB, hist, E, nb, 16);
  HSCAN();
  k_rscatP<<<nb, RB, 0, stream>>>(kvB, hist, E, nb, 16,
                                  pairByRank, scoreByRank, chosen, nmin);

  // eager pre-round 0: per-node choose (complete nmin), then compact (complete matched_g)
  k_choose0N<<<gridN, TB, 0, stream>>>(pairByRank, nmin, chosen, matched_g, N);
  k_compact0<<<gridE, TB, 0, stream>>>(pairByRank, matched_g, liveB, nmin, &cnts[8], E);

  // eager pre-rounds 1..PRROUNDS-1: ping-pong starting from liveB
  u64* Lin = liveB; u64* Lout = liveA;
  for (int r = 1; r < PRROUNDS; ++r) {
    k_chooseR<<<gridE, TB, 0, stream>>>(Lin, &cnts[8 + r - 1], nmin, chosen, matched_g, TAG(r));
    k_compactR<<<gridE, TB, 0, stream>>>(Lin, &cnts[8 + r - 1], matched_g, Lout, nmin,
                                         &cnts[8 + r], TAG(r + 1));
    u64* tmp = Lin; Lin = Lout; Lout = tmp;
  }
  // Lin holds round-(PRROUNDS-1) survivors (tracked pointers, r4-bug lesson)

  // residual rounds (single block)
  k_match<<<1, WG, 0, stream>>>(Lin, Lout, nmin, matched_g, &cnts[8 + PRROUNDS - 1],
                                chosen, N);

  // cluster-id assignment (block sums + self-prefixing assign)
  k_sums<<<nbc + nbn, CB, 0, stream>>>(chosen, csum, E, matched_g, nsum, N, nbc);
  k_assign<<<nbc + nbn, CB, 0, stream>>>(chosen, csum, pairByRank, scoreByRank, E,
                                         matched_g, nsum, N, cnts,
                                         cluster, pairA, pairB, cscore, nbc, nbn);

  // fused outputs (fully overwrite d_out; scratch regions dead by now)
  k_out<<<nxb + gridE, TB, 0, stream>>>(x, pairA, pairB, cscore, cnts, ei, cluster,
                                        (float*)d_out, N, E, nxb);
}